// Round 2
// 865.652 us; speedup vs baseline: 1.1045x; 1.1045x over previous
//
#include <hip/hip_runtime.h>
#include <cstdint>
#include <cstddef>

// ---------------------------------------------------------------------------
// LlamaAttention prefill, MI355X/gfx950.
// Round 5 (= round 4 resubmit; round 4 bench died to container infra failure
// with no counters. Kernel audited for hang paths (all barriers/waitcnts
// block-uniform; vmcnt(N) can't block forever) and OOB (all address ranges
// end exactly at region boundaries) -- resubmitting unchanged):
//  - GEMMs rebuilt on the 256x256 deep-pipeline template (T1+T2+T3/T4+T5):
//    512 thr / 8 waves (2Mx4N), BK=32, FOUR LDS buffers (128 KiB) so staging
//    runs 3 K-tiles ahead of compute; per-tile boundary waits s_waitcnt
//    vmcnt(8) (tiles t+2,t+3 stay in flight -- never drains to 0 in the main
//    loop); 2 phases/tile {ds_read ; stage ; bar ; lgkm0 ; setprio1 ; 16 MFMA ;
//    setprio0 ; bar}.
//  - Frag-read bank swizzle: chunk' = chunk ^ (r&3) ^ ((r>>2)&3) -> each
//    16-lane quarter of a ds_read_b128 hits every bank exactly twice (the
//    free minimum). Realized via pre-swizzled global source (global_load_lds
//    writes linearly) + swizzled ds_read offset.
//  - Bijective XCD swizzle on flattened grid (nwg%8==0 for both GEMMs).
//  - Attention / RoPE / cast / transposes unchanged from round 3.
// Workspace layout (bytes): total 176,160,768 (168 MiB)
//   [0,32M)      Xbf  (4096x4096 bf16)  -- reused as AO after GEMM1
//   [32M,80M)    Wqkvt (6144x4096 bf16, B^T)
//   [80M,112M)   Wot   (4096x4096 bf16, B^T)
//   [112M,160M)  QKV   (4096x6144 bf16; V section unused/poisoned)
//   [160M,168M)  Vt    (32 bh x 128 d x 1024 p bf16)
// ---------------------------------------------------------------------------

typedef unsigned short u16;
typedef __bf16 bf16x8 __attribute__((ext_vector_type(8)));
typedef float  f32x4  __attribute__((ext_vector_type(4)));

#define SEQ 1024
#define QKV_COLS 6144
#define NHEAD 32
#define NKVH 8
#define HDIM 128

__device__ __forceinline__ u16 f2bf(float f) {
  union { float f; uint32_t u; } v; v.f = f;
  return (u16)((v.u + 0x7fffu + ((v.u >> 16) & 1u)) >> 16);  // RNE
}
__device__ __forceinline__ float bf2f(u16 x) {
  union { uint32_t u; float f; } v; v.u = ((uint32_t)x) << 16;
  return v.f;
}

// async global->LDS DMA, 16B per lane. LDS dest: wave-uniform base + lane*16.
typedef __attribute__((address_space(1))) const uint32_t g_u32;
typedef __attribute__((address_space(3))) uint32_t l_u32;
__device__ __forceinline__ void async_copy16(const u16* g, u16* lds_base) {
  __builtin_amdgcn_global_load_lds((g_u32*)g, (l_u32*)lds_base, 16, 0, 0);
}

// ---------------- fp32 -> bf16 flat cast (X) ----------------
__global__ void cast_f32_bf16(const float* __restrict__ in, u16* __restrict__ out, int n) {
  int i = (blockIdx.x * 256 + threadIdx.x) * 4;
  if (i >= n) return;
  float4 v = *(const float4*)&in[i];
  uint2 pk;
  pk.x = (uint32_t)f2bf(v.x) | ((uint32_t)f2bf(v.y) << 16);
  pk.y = (uint32_t)f2bf(v.z) | ((uint32_t)f2bf(v.w) << 16);
  *(uint2*)&out[i] = pk;
}

// ---------------- transpose fp32 [R][C] -> bf16 [C][R] ----------------
__global__ void transpose_f32_bf16(const float* __restrict__ in, u16* __restrict__ out,
                                   int R, int C) {
  __shared__ float tile[32][33];
  int c0 = blockIdx.x * 32, r0 = blockIdx.y * 32;
  int tx = threadIdx.x, ty = threadIdx.y;
  tile[ty][tx] = in[(size_t)(r0 + ty) * C + c0 + tx];
  __syncthreads();
  out[(size_t)(c0 + ty) * R + r0 + tx] = f2bf(tile[tx][ty]);
}

// ---------------- bf16 GEMM: C[M][N] = A[M][K] * Bt[N][K]^T ----------------
// 256x256 tile, 8 waves (2Mx4N), wave tile 128x64 (8x4 frags of 16x16x32).
// BK=32. 4 LDS buffers (A,B each 256x32 bf16 = 16 KiB) = 128 KiB total.
// Pipeline: while computing tile t, stage tile t+3 (its buffer was last read
// in tile t-1, sealed by the boundary barrier at end of t-1). Boundary wait
// vmcnt(8) leaves tiles t+2,t+3 (8 global_load_lds per wave) in flight and
// guarantees tile t+1 staged (block-wide after s_barrier).
// Frag-read swizzle: LDS chunk slot j of row r holds global chunk
// j ^ (r&3) ^ ((r>>2)&3)  -> each 16-lane quarter of a ds_read_b128 hits
// every bank exactly twice (the free minimum). Since frag row bases are
// multiples of 16, the read-side offset depends only on the lane.
// MODE 0: bf16 C to QKV, V col-tiles (>=5120) go straight to Vt[bh][d][p].
// MODE 1: f32 C.
template <int MODE>
__global__ __launch_bounds__(512, 2) void gemm_bt(const u16* __restrict__ A,
                                                  const u16* __restrict__ Bt,
                                                  void* __restrict__ Cv,
                                                  u16* __restrict__ Vt,
                                                  int M, int N, int K, int ldc,
                                                  int nbx) {
  __shared__ __align__(16) u16 smem[4][2][256 * 32];   // [buf][A|B], 128 KiB

  const int tid = threadIdx.x;
  const int lane = tid & 63, wave = tid >> 6;
  const int l15 = lane & 15, qd = lane >> 4;
  const int wm = wave >> 2, wn = wave & 3;

  // XCD-aware bijective block swizzle (nwg % 8 == 0 for our shapes)
  const int nwg = gridDim.x;
  const int bid = (int)blockIdx.x;
  const int swz = (bid & 7) * (nwg >> 3) + (bid >> 3);
  const int bx = swz % nbx, by = swz / nbx;
  const int row0 = by * 256, col0 = bx * 256;

  // swizzled fragment read chunk offset (elements); row base = 0 mod 16 so
  // s(row) = (l15&3) ^ ((l15>>2)&3)
  const int sl = (qd ^ (l15 & 3) ^ (l15 >> 2)) * 8;

  // staging: per-thread pre-swizzled global source offset + wave LDS base
  int soff[2], cb[2];
#pragma unroll
  for (int call = 0; call < 2; ++call) {
    const int c = call * 512 + tid;              // linear LDS 16B-chunk index
    const int r = c >> 2, j = c & 3;             // row, chunk slot
    const int src = j ^ (r & 3) ^ ((r >> 2) & 3);
    soff[call] = r * K + src * 8;
    cb[call] = (call * 512 + wave * 64) * 8;     // wave-uniform dest (u16 idx)
  }

  const u16* Ab = A + (size_t)row0 * K;
  const u16* Bb = Bt + (size_t)col0 * K;
  const int NT = K >> 5;                         // K-tiles (K=4096 -> 128)

  f32x4 acc[8][4] = {};

  // -------- prologue: stage tiles 0..2 (12 loads), wait oldest 4 --------
#pragma unroll
  for (int tt = 0; tt < 3; ++tt) {
#pragma unroll
    for (int call = 0; call < 2; ++call)
      async_copy16(&Ab[tt * 32 + soff[call]], &smem[tt][0][cb[call]]);
#pragma unroll
    for (int call = 0; call < 2; ++call)
      async_copy16(&Bb[tt * 32 + soff[call]], &smem[tt][1][cb[call]]);
  }
  asm volatile("s_waitcnt vmcnt(8)" ::: "memory");
  __builtin_amdgcn_s_barrier();

  for (int t = 0; t < NT; ++t) {
    const int bsel = t & 3, ssel = (t + 3) & 3;
    const u16* As = &smem[bsel][0][0];
    const u16* Bs = &smem[bsel][1][0];
    const bool do_stage = (t + 3) < NT;
    const int knext = (t + 3) * 32;

    bf16x8 af[4], bfr[4];
    // ---- phase A: frags (mi 0-3 x ni 0-3), stage A-tile of t+3 ----
#pragma unroll
    for (int i = 0; i < 4; ++i) {
      af[i]  = *(const bf16x8*)&As[(wm * 128 + i * 16 + l15) * 32 + sl];
      bfr[i] = *(const bf16x8*)&Bs[(wn * 64 + i * 16 + l15) * 32 + sl];
    }
    if (do_stage) {
#pragma unroll
      for (int call = 0; call < 2; ++call)
        async_copy16(&Ab[knext + soff[call]], &smem[ssel][0][cb[call]]);
    }
    __builtin_amdgcn_s_barrier();
    asm volatile("s_waitcnt lgkmcnt(0)" ::: "memory");
    __builtin_amdgcn_sched_barrier(0);
    __builtin_amdgcn_s_setprio(1);
#pragma unroll
    for (int mi = 0; mi < 4; ++mi)
#pragma unroll
      for (int ni = 0; ni < 4; ++ni)
        acc[mi][ni] = __builtin_amdgcn_mfma_f32_16x16x32_bf16(af[mi], bfr[ni], acc[mi][ni], 0, 0, 0);
    __builtin_amdgcn_s_setprio(0);
    __builtin_amdgcn_sched_barrier(0);
    __builtin_amdgcn_s_barrier();

    // ---- phase B: frags (mi 4-7 x ni 0-3), stage B-tile of t+3 ----
#pragma unroll
    for (int i = 0; i < 4; ++i)
      af[i] = *(const bf16x8*)&As[(wm * 128 + (4 + i) * 16 + l15) * 32 + sl];
    if (do_stage) {
#pragma unroll
      for (int call = 0; call < 2; ++call)
        async_copy16(&Bb[knext + soff[call]], &smem[ssel][1][cb[call]]);
    }
    __builtin_amdgcn_s_barrier();
    asm volatile("s_waitcnt lgkmcnt(0)" ::: "memory");
    __builtin_amdgcn_sched_barrier(0);
    __builtin_amdgcn_s_setprio(1);
#pragma unroll
    for (int mi = 0; mi < 4; ++mi)
#pragma unroll
      for (int ni = 0; ni < 4; ++ni)
        acc[4 + mi][ni] = __builtin_amdgcn_mfma_f32_16x16x32_bf16(af[mi], bfr[ni], acc[4 + mi][ni], 0, 0, 0);
    __builtin_amdgcn_s_setprio(0);
    __builtin_amdgcn_sched_barrier(0);

    // ---- tile boundary: counted vmcnt (never 0 until the tail) ----
    if (t < NT - 1) {
      if (t < NT - 3)       asm volatile("s_waitcnt vmcnt(8)" ::: "memory");
      else if (t == NT - 3) asm volatile("s_waitcnt vmcnt(4)" ::: "memory");
      else                  asm volatile("s_waitcnt vmcnt(0)" ::: "memory");
      __builtin_amdgcn_s_barrier();
    }
  }

  // epilogue: C/D layout col=lane&15, row=(lane>>4)*4+reg
  if (MODE == 0 && col0 >= 5120) {               // V section -> Vt directly
#pragma unroll
    for (int mi = 0; mi < 8; ++mi)
#pragma unroll
      for (int ni = 0; ni < 4; ++ni) {
        const int col = col0 + wn * 64 + ni * 16 + l15;
        const int dcol = col - 5120, kvh = dcol >> 7, d = dcol & 127;
        const int row = row0 + wm * 128 + mi * 16 + qd * 4;  // token, r=0
        const int bb = row >> 10, p = row & 1023;
        ushort4 pk;
        pk.x = f2bf(acc[mi][ni][0]); pk.y = f2bf(acc[mi][ni][1]);
        pk.z = f2bf(acc[mi][ni][2]); pk.w = f2bf(acc[mi][ni][3]);
        *(ushort4*)&Vt[(((size_t)(bb * 8 + kvh) * 128) + d) * 1024 + p] = pk;
      }
    return;
  }
#pragma unroll
  for (int mi = 0; mi < 8; ++mi)
#pragma unroll
    for (int ni = 0; ni < 4; ++ni)
#pragma unroll
      for (int r = 0; r < 4; ++r) {
        int row = row0 + wm * 128 + mi * 16 + qd * 4 + r;
        int col = col0 + wn * 64 + ni * 16 + l15;
        float v = acc[mi][ni][r];
        if (MODE == 1) ((float*)Cv)[(size_t)row * ldc + col] = v;
        else           ((u16*)Cv)[(size_t)row * ldc + col] = f2bf(v);
      }
}

// ---------------- RoPE in-place on Q,K columns of QKV ----------------
__global__ void rope_kernel(u16* __restrict__ qkv, const float* __restrict__ inv_freq,
                            const int* __restrict__ pos) {
  int idx = blockIdx.x * 256 + threadIdx.x;     // T * 40 heads * 64 pairs
  int t = idx / 2560;
  int r = idx - t * 2560;
  int hh = r >> 6, i = r & 63;
  float f = (float)pos[t] * inv_freq[i];
  float s, c;
  sincosf(f, &s, &c);
  size_t base = (size_t)t * QKV_COLS + hh * HDIM + i;
  float x1 = bf2f(qkv[base]), x2 = bf2f(qkv[base + 64]);
  qkv[base]      = f2bf(x1 * c - x2 * s);
  qkv[base + 64] = f2bf(x2 * c + x1 * s);
}

// ---------------- flash attention ----------------
// block = (q-tile 128, head, batch); 8 waves x 16 q-rows; kv-tile 64.
// QK^T: A=Q frags (regs), B=K (LDS [kv][d] stride 136; 2-way banks = free).
// softmax: C-layout rows, quad-shuffle reductions; P -> per-wave LDS
// [q][kv] stride 68 (C->A layout round trip). PV: O^T acc, A=Vt (LDS [d][kv]
// stride 68). LDS total 52224 B.
__global__ __launch_bounds__(512, 4) void attn_kernel(const u16* __restrict__ qkv,
                                                      const u16* __restrict__ vt,
                                                      u16* __restrict__ ao) {
  __shared__ __align__(16) u16 Ks[64 * 136];
  __shared__ __align__(16) u16 Vts[128 * 68];
  __shared__ __align__(16) u16 Ps[8][16 * 68];

  const int tid = threadIdx.x;
  const int lane = tid & 63, wave = tid >> 6;
  const int l15 = lane & 15, qd = lane >> 4;
  const int qt = blockIdx.x, h = blockIdx.y, b = blockIdx.z;
  const int q0 = qt * 128;
  const int kvh = h >> 2;                      // GQA groups=4
  const float scale = 0.08838834764831845f;    // 1/sqrt(128)

  bf16x8 qf[4];
  {
    const size_t qrow = (size_t)(b * SEQ + q0 + wave * 16 + l15) * QKV_COLS + h * HDIM;
#pragma unroll
    for (int s = 0; s < 4; ++s) qf[s] = *(const bf16x8*)&qkv[qrow + s * 32 + qd * 8];
  }

  f32x4 o[8] = {};
  float mrow[4] = {-__builtin_inff(), -__builtin_inff(), -__builtin_inff(), -__builtin_inff()};
  float lrow[4] = {0.f, 0.f, 0.f, 0.f};

  const int nkt = qt * 2 + 2;                  // causal: kv tiles 0..(q0+128)/64
  const size_t vbase0 = ((size_t)(b * NKVH + kvh) * HDIM) * SEQ;
  for (int kt = 0; kt < nkt; ++kt) {
    const int kv0 = kt * 64;
#pragma unroll
    for (int rnd = 0; rnd < 2; ++rnd) {        // K tile [64][128], stride 136
      int c = tid + rnd * 512;
      int kv = c >> 4, dc = (c & 15) * 8;
      *(uint4*)&Ks[kv * 136 + dc] =
          *(const uint4*)&qkv[(size_t)(b * SEQ + kv0 + kv) * QKV_COLS + 4096 + kvh * HDIM + dc];
    }
#pragma unroll
    for (int rnd = 0; rnd < 2; ++rnd) {        // Vt tile [128][64], stride 68
      int c = tid + rnd * 512;
      int d = c >> 3, kc = (c & 7) * 8;
      *(uint4*)&Vts[d * 68 + kc] = *(const uint4*)&vt[vbase0 + (size_t)d * SEQ + kv0 + kc];
    }
    __syncthreads();

    f32x4 st[4] = {};
#pragma unroll
    for (int t = 0; t < 4; ++t)
#pragma unroll
      for (int s = 0; s < 4; ++s) {
        bf16x8 kf = *(const bf16x8*)&Ks[(t * 16 + l15) * 136 + s * 32 + qd * 8];
        st[t] = __builtin_amdgcn_mfma_f32_16x16x32_bf16(qf[s], kf, st[t], 0, 0, 0);
      }

    float al[4];
#pragma unroll
    for (int r = 0; r < 4; ++r) {
      const int qpos = q0 + wave * 16 + qd * 4 + r;
      float sc[4];
#pragma unroll
      for (int t = 0; t < 4; ++t) {
        sc[t] = st[t][r] * scale;
        if (kv0 + t * 16 + l15 > qpos) sc[t] = -1e30f;
      }
      float mt = fmaxf(fmaxf(sc[0], sc[1]), fmaxf(sc[2], sc[3]));
      mt = fmaxf(mt, __shfl_xor(mt, 8));
      mt = fmaxf(mt, __shfl_xor(mt, 4));
      mt = fmaxf(mt, __shfl_xor(mt, 2));
      mt = fmaxf(mt, __shfl_xor(mt, 1));
      const float mn = fmaxf(mrow[r], mt);
      al[r] = __expf(mrow[r] - mn);
      float p[4], rs = 0.f;
#pragma unroll
      for (int t = 0; t < 4; ++t) { p[t] = __expf(sc[t] - mn); rs += p[t]; }
      rs += __shfl_xor(rs, 8);
      rs += __shfl_xor(rs, 4);
      rs += __shfl_xor(rs, 2);
      rs += __shfl_xor(rs, 1);
      lrow[r] = lrow[r] * al[r] + rs;
      mrow[r] = mn;
#pragma unroll
      for (int t = 0; t < 4; ++t)
        Ps[wave][(qd * 4 + r) * 68 + t * 16 + l15] = f2bf(p[t]);
    }
    asm volatile("s_waitcnt lgkmcnt(0)" ::: "memory");  // P visible wave-wide

    {  // broadcast alpha (row-indexed) to q=l15 lanes, rescale O^T
      const int srcl = (l15 >> 2) * 16;
      float a0 = __shfl(al[0], srcl), a1 = __shfl(al[1], srcl);
      float a2 = __shfl(al[2], srcl), a3 = __shfl(al[3], srcl);
      const int rr = l15 & 3;
      float aq = (rr & 2) ? ((rr & 1) ? a3 : a2) : ((rr & 1) ? a1 : a0);
#pragma unroll
      for (int dt = 0; dt < 8; ++dt) o[dt] *= aq;
    }
    {  // PV: O^T[d][q] += Vt[d][kv] * P^T[kv][q], kv split in 2 k-tiles of 32
      const bf16x8 pf0 = *(const bf16x8*)&Ps[wave][l15 * 68 + qd * 8];
      const bf16x8 pf1 = *(const bf16x8*)&Ps[wave][l15 * 68 + 32 + qd * 8];
#pragma unroll
      for (int dt = 0; dt < 8; ++dt) {
        const bf16x8 vf0 = *(const bf16x8*)&Vts[(dt * 16 + l15) * 68 + qd * 8];
        const bf16x8 vf1 = *(const bf16x8*)&Vts[(dt * 16 + l15) * 68 + 32 + qd * 8];
        o[dt] = __builtin_amdgcn_mfma_f32_16x16x32_bf16(vf0, pf0, o[dt], 0, 0, 0);
        o[dt] = __builtin_amdgcn_mfma_f32_16x16x32_bf16(vf1, pf1, o[dt], 0, 0, 0);
      }
    }
    __syncthreads();
  }

  {  // normalize by l (q-indexed), packed ushort4 stores of O^T
    const int srcl = (l15 >> 2) * 16;
    float l0 = __shfl(lrow[0], srcl), l1 = __shfl(lrow[1], srcl);
    float l2 = __shfl(lrow[2], srcl), l3 = __shfl(lrow[3], srcl);
    const int rr = l15 & 3;
    float lq = (rr & 2) ? ((rr & 1) ? l3 : l2) : ((rr & 1) ? l1 : l0);
    const float inv = 1.0f / lq;
    const size_t obase = (size_t)(b * SEQ + q0 + wave * 16 + l15) * (NHEAD * HDIM) + h * HDIM;
#pragma unroll
    for (int dt = 0; dt < 8; ++dt) {
      ushort4 pk;
      pk.x = f2bf(o[dt][0] * inv); pk.y = f2bf(o[dt][1] * inv);
      pk.z = f2bf(o[dt][2] * inv); pk.w = f2bf(o[dt][3] * inv);
      *(ushort4*)&ao[obase + dt * 16 + qd * 4] = pk;
    }
  }
}

// ---------------------------------------------------------------------------
extern "C" void kernel_launch(void* const* d_in, const int* in_sizes, int n_in,
                              void* d_out, int out_size, void* d_ws, size_t ws_size,
                              hipStream_t stream) {
  const float* X    = (const float*)d_in[0];
  const float* Wq   = (const float*)d_in[1];
  const float* Wk   = (const float*)d_in[2];
  const float* Wv   = (const float*)d_in[3];
  const float* Wo   = (const float*)d_in[4];
  const float* invf = (const float*)d_in[5];
  const int*   pos  = (const int*)d_in[8];
  float* out = (float*)d_out;

  char* ws = (char*)d_ws;
  u16* Xbf   = (u16*)(ws + 0);
  u16* Wqkvt = (u16*)(ws + 33554432);
  u16* Wot   = (u16*)(ws + 83886080);
  u16* QKV   = (u16*)(ws + 117440512);
  u16* Vt    = (u16*)(ws + 167772160);
  u16* AO    = Xbf;  // reuse: Xbf dead after GEMM1

  dim3 tb32(32, 32);
  cast_f32_bf16<<<16384, 256, 0, stream>>>(X, Xbf, 16777216);
  transpose_f32_bf16<<<dim3(128, 128), tb32, 0, stream>>>(Wq, Wqkvt, 4096, 4096);
  transpose_f32_bf16<<<dim3(32, 128),  tb32, 0, stream>>>(Wk, Wqkvt + (size_t)4096 * 4096, 4096, 1024);
  transpose_f32_bf16<<<dim3(32, 128),  tb32, 0, stream>>>(Wv, Wqkvt + (size_t)5120 * 4096, 4096, 1024);
  transpose_f32_bf16<<<dim3(128, 128), tb32, 0, stream>>>(Wo, Wot, 4096, 4096);

  // grid = flattened (N/256)*(M/256); nbx passed for in-kernel decode
  gemm_bt<0><<<dim3(24 * 16), 512, 0, stream>>>(Xbf, Wqkvt, QKV, Vt, 4096, 6144, 4096, 6144, 24);
  rope_kernel<<<40960, 256, 0, stream>>>(QKV, invf, pos);
  attn_kernel<<<dim3(8, 32, 4), 512, 0, stream>>>(QKV, Vt, AO);
  gemm_bt<1><<<dim3(16 * 16), 512, 0, stream>>>(AO, Wot, out, Vt, 4096, 4096, 4096, 4096, 16);
}

// Round 3
// 812.053 us; speedup vs baseline: 1.1774x; 1.0660x over previous
//
#include <hip/hip_runtime.h>
#include <cstdint>
#include <cstddef>

// ---------------------------------------------------------------------------
// LlamaAttention prefill, MI355X/gfx950.
// Round 6: de-lockstep the 256x256 GEMM pipeline.
//  R5 diagnosis: MfmaUtil 31%, VALUBusy 13%, HBM 18% -> half the machine idle.
//  Per-CU per-K-tile arithmetic showed FULL serialization (~3500 cyc observed
//  vs ~1030 MFMA + ~1150 LDS + ~250 stage + sync ~= 3300 serial): the
//  per-phase {bar; lgkmcnt(0); MFMA; bar} structure drains all ds_reads
//  before any MFMA and issues no reads during MFMA.
//  Fix (this round):
//   - ONE vmcnt + ONE s_barrier per K-tile (cross-wave hazards only exist at
//     tile granularity with the 4-buffer ring + 3-ahead staging).
//   - Software-pipelined frag reads with compiler-counted lgkmcnt: phase A
//     issues phase-B's a1 reads; phase B issues NEXT tile's a0/b0 reads
//     (buffer t+1, published at boundary(t-1) via vmcnt(4) which lands loads
//     of t+1 AND t+2). MFMA bursts run with 4-8 ds_reads in flight.
//   - Write-after-read proof: staging into (t+3)&3 == (t-1)&3 is issued after
//     boundary(t-1); every wave's buffer-(t-1) reads were lgkm-drained before
//     its phase-B MFMA of tile t-1.
//   - sched_barrier(0) pins {reads || stage} before each MFMA burst;
//     asm("":::"memory") after each raw s_barrier stops read hoisting
//     (raw s_barrier is IntrNoMem -- not a compiler fence).
//  Attention / RoPE / cast / transposes unchanged.
// Workspace layout (bytes): total 176,160,768 (168 MiB)
//   [0,32M)      Xbf  (4096x4096 bf16)  -- reused as AO after GEMM1
//   [32M,80M)    Wqkvt (6144x4096 bf16, B^T)
//   [80M,112M)   Wot   (4096x4096 bf16, B^T)
//   [112M,160M)  QKV   (4096x6144 bf16; V section unused/poisoned)
//   [160M,168M)  Vt    (32 bh x 128 d x 1024 p bf16)
// ---------------------------------------------------------------------------

typedef unsigned short u16;
typedef __bf16 bf16x8 __attribute__((ext_vector_type(8)));
typedef float  f32x4  __attribute__((ext_vector_type(4)));

#define SEQ 1024
#define QKV_COLS 6144
#define NHEAD 32
#define NKVH 8
#define HDIM 128

__device__ __forceinline__ u16 f2bf(float f) {
  union { float f; uint32_t u; } v; v.f = f;
  return (u16)((v.u + 0x7fffu + ((v.u >> 16) & 1u)) >> 16);  // RNE
}
__device__ __forceinline__ float bf2f(u16 x) {
  union { uint32_t u; float f; } v; v.u = ((uint32_t)x) << 16;
  return v.f;
}

// async global->LDS DMA, 16B per lane. LDS dest: wave-uniform base + lane*16.
typedef __attribute__((address_space(1))) const uint32_t g_u32;
typedef __attribute__((address_space(3))) uint32_t l_u32;
__device__ __forceinline__ void async_copy16(const u16* g, u16* lds_base) {
  __builtin_amdgcn_global_load_lds((g_u32*)g, (l_u32*)lds_base, 16, 0, 0);
}

// ---------------- fp32 -> bf16 flat cast (X) ----------------
__global__ void cast_f32_bf16(const float* __restrict__ in, u16* __restrict__ out, int n) {
  int i = (blockIdx.x * 256 + threadIdx.x) * 4;
  if (i >= n) return;
  float4 v = *(const float4*)&in[i];
  uint2 pk;
  pk.x = (uint32_t)f2bf(v.x) | ((uint32_t)f2bf(v.y) << 16);
  pk.y = (uint32_t)f2bf(v.z) | ((uint32_t)f2bf(v.w) << 16);
  *(uint2*)&out[i] = pk;
}

// ---------------- transpose fp32 [R][C] -> bf16 [C][R] ----------------
__global__ void transpose_f32_bf16(const float* __restrict__ in, u16* __restrict__ out,
                                   int R, int C) {
  __shared__ float tile[32][33];
  int c0 = blockIdx.x * 32, r0 = blockIdx.y * 32;
  int tx = threadIdx.x, ty = threadIdx.y;
  tile[ty][tx] = in[(size_t)(r0 + ty) * C + c0 + tx];
  __syncthreads();
  out[(size_t)(c0 + ty) * R + r0 + tx] = f2bf(tile[tx][ty]);
}

// ---------------- bf16 GEMM: C[M][N] = A[M][K] * Bt[N][K]^T ----------------
// 256x256 tile, 8 waves (2Mx4N), wave tile 128x64 (8x4 frags of 16x16x32).
// BK=32. 4 LDS buffers; staging 3 tiles ahead; boundary = vmcnt(4)+s_barrier
// (publishes tiles t+1,t+2 -> next-tile register prefetch is legal).
// Per tile: phase A {read a1(buf t); stage A(t+3); SGB; MFMA acc[0..3]} then
// phase B {read next a0/b0(buf t+1); stage B(t+3); SGB; MFMA acc[4..7]}.
// Compiler emits counted lgkmcnt (a0/b0 oldest -> lgkm(4); a1 -> lgkm(8)),
// so each 16-MFMA burst runs with the next reads in flight.
// Frag-read swizzle: LDS chunk slot j of row r holds global chunk
// j ^ (r&3) ^ ((r>>2)&3); row bases are multiples of 16 so the read offset
// depends only on the lane: sl = (qd ^ (l15&3) ^ (l15>>2))*8.
// MODE 0: bf16 C to QKV, V col-tiles (>=5120) go straight to Vt[bh][d][p].
// MODE 1: f32 C.
template <int MODE>
__global__ __launch_bounds__(512, 2) void gemm_bt(const u16* __restrict__ A,
                                                  const u16* __restrict__ Bt,
                                                  void* __restrict__ Cv,
                                                  u16* __restrict__ Vt,
                                                  int M, int N, int K, int ldc,
                                                  int nbx) {
  __shared__ __align__(16) u16 smem[4][2][256 * 32];   // [buf][A|B], 128 KiB

  const int tid = threadIdx.x;
  const int lane = tid & 63, wave = tid >> 6;
  const int l15 = lane & 15, qd = lane >> 4;
  const int wm = wave >> 2, wn = wave & 3;

  // XCD-aware bijective block swizzle (nwg % 8 == 0 for our shapes)
  const int nwg = gridDim.x;
  const int bid = (int)blockIdx.x;
  const int swz = (bid & 7) * (nwg >> 3) + (bid >> 3);
  const int bx = swz % nbx, by = swz / nbx;
  const int row0 = by * 256, col0 = bx * 256;

  const int sl = (qd ^ (l15 & 3) ^ (l15 >> 2)) * 8;   // swizzled frag chunk

  // staging: per-thread pre-swizzled global source offset + wave LDS base
  int soff[2], cb[2];
#pragma unroll
  for (int call = 0; call < 2; ++call) {
    const int c = call * 512 + tid;              // linear LDS 16B-chunk index
    const int r = c >> 2, j = c & 3;             // row, chunk slot
    const int src = j ^ (r & 3) ^ ((r >> 2) & 3);
    soff[call] = r * K + src * 8;
    cb[call] = (call * 512 + wave * 64) * 8;     // wave-uniform dest (u16 idx)
  }

  const u16* Ab = A + (size_t)row0 * K;
  const u16* Bb = Bt + (size_t)col0 * K;
  const int NT = K >> 5;                         // K-tiles (K=4096 -> 128)

  f32x4 acc[8][4] = {};

  // -------- prologue: stage tiles 0..2 (12 loads), publish 0 and 1 --------
#pragma unroll
  for (int tt = 0; tt < 3; ++tt) {
#pragma unroll
    for (int call = 0; call < 2; ++call)
      async_copy16(&Ab[tt * 32 + soff[call]], &smem[tt][0][cb[call]]);
#pragma unroll
    for (int call = 0; call < 2; ++call)
      async_copy16(&Bb[tt * 32 + soff[call]], &smem[tt][1][cb[call]]);
  }
  asm volatile("s_waitcnt vmcnt(4)" ::: "memory");   // tiles 0,1 landed
  __builtin_amdgcn_s_barrier();
  asm volatile("" ::: "memory");

  // register prefetch: phase-A frags of tile 0
  bf16x8 a0[4], b0[4];
#pragma unroll
  for (int i = 0; i < 4; ++i) {
    a0[i] = *(const bf16x8*)&smem[0][0][(wm * 128 + i * 16 + l15) * 32 + sl];
    b0[i] = *(const bf16x8*)&smem[0][1][(wn * 64 + i * 16 + l15) * 32 + sl];
  }

#pragma unroll 2
  for (int t = 0; t < NT; ++t) {
    const int bsel = t & 3, nsel = (t + 1) & 3, ssel = (t + 3) & 3;
    const bool do_stage = (t + 3) < NT;
    const int knext = (t + 3) * 32;

    // ---- phase A: issue a1 reads + A-staging, then MFMA on a0/b0 ----
    bf16x8 a1[4];
#pragma unroll
    for (int i = 0; i < 4; ++i)
      a1[i] = *(const bf16x8*)&smem[bsel][0][(wm * 128 + 64 + i * 16 + l15) * 32 + sl];
    if (do_stage) {
#pragma unroll
      for (int call = 0; call < 2; ++call)
        async_copy16(&Ab[knext + soff[call]], &smem[ssel][0][cb[call]]);
    }
    __builtin_amdgcn_sched_barrier(0);
    __builtin_amdgcn_s_setprio(1);
#pragma unroll
    for (int mi = 0; mi < 4; ++mi)
#pragma unroll
      for (int ni = 0; ni < 4; ++ni)
        acc[mi][ni] = __builtin_amdgcn_mfma_f32_16x16x32_bf16(a0[mi], b0[ni], acc[mi][ni], 0, 0, 0);
    __builtin_amdgcn_s_setprio(0);

    // ---- phase B: issue NEXT tile's a0/b0 reads + B-staging, MFMA on a1/b0 --
    bf16x8 a2[4], b2[4];
    if (t + 1 < NT) {
#pragma unroll
      for (int i = 0; i < 4; ++i) {
        a2[i] = *(const bf16x8*)&smem[nsel][0][(wm * 128 + i * 16 + l15) * 32 + sl];
        b2[i] = *(const bf16x8*)&smem[nsel][1][(wn * 64 + i * 16 + l15) * 32 + sl];
      }
    }
    if (do_stage) {
#pragma unroll
      for (int call = 0; call < 2; ++call)
        async_copy16(&Bb[knext + soff[call]], &smem[ssel][1][cb[call]]);
    }
    __builtin_amdgcn_sched_barrier(0);
    __builtin_amdgcn_s_setprio(1);
#pragma unroll
    for (int mi = 0; mi < 4; ++mi)
#pragma unroll
      for (int ni = 0; ni < 4; ++ni)
        acc[4 + mi][ni] = __builtin_amdgcn_mfma_f32_16x16x32_bf16(a1[mi], b0[ni], acc[4 + mi][ni], 0, 0, 0);
    __builtin_amdgcn_s_setprio(0);

    // ---- tile boundary: publish t+2 (t+1 already published), seal reads ----
    if (t < NT - 2) {
      if (t < NT - 3) asm volatile("s_waitcnt vmcnt(4)" ::: "memory");
      else            asm volatile("s_waitcnt vmcnt(0)" ::: "memory");
      __builtin_amdgcn_s_barrier();
      asm volatile("" ::: "memory");
    }
#pragma unroll
    for (int i = 0; i < 4; ++i) { a0[i] = a2[i]; b0[i] = b2[i]; }
  }

  // epilogue: C/D layout col=lane&15, row=(lane>>4)*4+reg
  if (MODE == 0 && col0 >= 5120) {               // V section -> Vt directly
#pragma unroll
    for (int mi = 0; mi < 8; ++mi)
#pragma unroll
      for (int ni = 0; ni < 4; ++ni) {
        const int col = col0 + wn * 64 + ni * 16 + l15;
        const int dcol = col - 5120, kvh = dcol >> 7, d = dcol & 127;
        const int row = row0 + wm * 128 + mi * 16 + qd * 4;  // token, r=0
        const int bb = row >> 10, p = row & 1023;
        ushort4 pk;
        pk.x = f2bf(acc[mi][ni][0]); pk.y = f2bf(acc[mi][ni][1]);
        pk.z = f2bf(acc[mi][ni][2]); pk.w = f2bf(acc[mi][ni][3]);
        *(ushort4*)&Vt[(((size_t)(bb * 8 + kvh) * 128) + d) * 1024 + p] = pk;
      }
    return;
  }
#pragma unroll
  for (int mi = 0; mi < 8; ++mi)
#pragma unroll
    for (int ni = 0; ni < 4; ++ni)
#pragma unroll
      for (int r = 0; r < 4; ++r) {
        int row = row0 + wm * 128 + mi * 16 + qd * 4 + r;
        int col = col0 + wn * 64 + ni * 16 + l15;
        float v = acc[mi][ni][r];
        if (MODE == 1) ((float*)Cv)[(size_t)row * ldc + col] = v;
        else           ((u16*)Cv)[(size_t)row * ldc + col] = f2bf(v);
      }
}

// ---------------- RoPE in-place on Q,K columns of QKV ----------------
__global__ void rope_kernel(u16* __restrict__ qkv, const float* __restrict__ inv_freq,
                            const int* __restrict__ pos) {
  int idx = blockIdx.x * 256 + threadIdx.x;     // T * 40 heads * 64 pairs
  int t = idx / 2560;
  int r = idx - t * 2560;
  int hh = r >> 6, i = r & 63;
  float f = (float)pos[t] * inv_freq[i];
  float s, c;
  sincosf(f, &s, &c);
  size_t base = (size_t)t * QKV_COLS + hh * HDIM + i;
  float x1 = bf2f(qkv[base]), x2 = bf2f(qkv[base + 64]);
  qkv[base]      = f2bf(x1 * c - x2 * s);
  qkv[base + 64] = f2bf(x2 * c + x1 * s);
}

// ---------------- flash attention ----------------
// block = (q-tile 128, head, batch); 8 waves x 16 q-rows; kv-tile 64.
// QK^T: A=Q frags (regs), B=K (LDS [kv][d] stride 136; 2-way banks = free).
// softmax: C-layout rows, quad-shuffle reductions; P -> per-wave LDS
// [q][kv] stride 68 (C->A layout round trip). PV: O^T acc, A=Vt (LDS [d][kv]
// stride 68). LDS total 52224 B.
__global__ __launch_bounds__(512, 4) void attn_kernel(const u16* __restrict__ qkv,
                                                      const u16* __restrict__ vt,
                                                      u16* __restrict__ ao) {
  __shared__ __align__(16) u16 Ks[64 * 136];
  __shared__ __align__(16) u16 Vts[128 * 68];
  __shared__ __align__(16) u16 Ps[8][16 * 68];

  const int tid = threadIdx.x;
  const int lane = tid & 63, wave = tid >> 6;
  const int l15 = lane & 15, qd = lane >> 4;
  const int qt = blockIdx.x, h = blockIdx.y, b = blockIdx.z;
  const int q0 = qt * 128;
  const int kvh = h >> 2;                      // GQA groups=4
  const float scale = 0.08838834764831845f;    // 1/sqrt(128)

  bf16x8 qf[4];
  {
    const size_t qrow = (size_t)(b * SEQ + q0 + wave * 16 + l15) * QKV_COLS + h * HDIM;
#pragma unroll
    for (int s = 0; s < 4; ++s) qf[s] = *(const bf16x8*)&qkv[qrow + s * 32 + qd * 8];
  }

  f32x4 o[8] = {};
  float mrow[4] = {-__builtin_inff(), -__builtin_inff(), -__builtin_inff(), -__builtin_inff()};
  float lrow[4] = {0.f, 0.f, 0.f, 0.f};

  const int nkt = qt * 2 + 2;                  // causal: kv tiles 0..(q0+128)/64
  const size_t vbase0 = ((size_t)(b * NKVH + kvh) * HDIM) * SEQ;
  for (int kt = 0; kt < nkt; ++kt) {
    const int kv0 = kt * 64;
#pragma unroll
    for (int rnd = 0; rnd < 2; ++rnd) {        // K tile [64][128], stride 136
      int c = tid + rnd * 512;
      int kv = c >> 4, dc = (c & 15) * 8;
      *(uint4*)&Ks[kv * 136 + dc] =
          *(const uint4*)&qkv[(size_t)(b * SEQ + kv0 + kv) * QKV_COLS + 4096 + kvh * HDIM + dc];
    }
#pragma unroll
    for (int rnd = 0; rnd < 2; ++rnd) {        // Vt tile [128][64], stride 68
      int c = tid + rnd * 512;
      int d = c >> 3, kc = (c & 7) * 8;
      *(uint4*)&Vts[d * 68 + kc] = *(const uint4*)&vt[vbase0 + (size_t)d * SEQ + kv0 + kc];
    }
    __syncthreads();

    f32x4 st[4] = {};
#pragma unroll
    for (int t = 0; t < 4; ++t)
#pragma unroll
      for (int s = 0; s < 4; ++s) {
        bf16x8 kf = *(const bf16x8*)&Ks[(t * 16 + l15) * 136 + s * 32 + qd * 8];
        st[t] = __builtin_amdgcn_mfma_f32_16x16x32_bf16(qf[s], kf, st[t], 0, 0, 0);
      }

    float al[4];
#pragma unroll
    for (int r = 0; r < 4; ++r) {
      const int qpos = q0 + wave * 16 + qd * 4 + r;
      float sc[4];
#pragma unroll
      for (int t = 0; t < 4; ++t) {
        sc[t] = st[t][r] * scale;
        if (kv0 + t * 16 + l15 > qpos) sc[t] = -1e30f;
      }
      float mt = fmaxf(fmaxf(sc[0], sc[1]), fmaxf(sc[2], sc[3]));
      mt = fmaxf(mt, __shfl_xor(mt, 8));
      mt = fmaxf(mt, __shfl_xor(mt, 4));
      mt = fmaxf(mt, __shfl_xor(mt, 2));
      mt = fmaxf(mt, __shfl_xor(mt, 1));
      const float mn = fmaxf(mrow[r], mt);
      al[r] = __expf(mrow[r] - mn);
      float p[4], rs = 0.f;
#pragma unroll
      for (int t = 0; t < 4; ++t) { p[t] = __expf(sc[t] - mn); rs += p[t]; }
      rs += __shfl_xor(rs, 8);
      rs += __shfl_xor(rs, 4);
      rs += __shfl_xor(rs, 2);
      rs += __shfl_xor(rs, 1);
      lrow[r] = lrow[r] * al[r] + rs;
      mrow[r] = mn;
#pragma unroll
      for (int t = 0; t < 4; ++t)
        Ps[wave][(qd * 4 + r) * 68 + t * 16 + l15] = f2bf(p[t]);
    }
    asm volatile("s_waitcnt lgkmcnt(0)" ::: "memory");  // P visible wave-wide

    {  // broadcast alpha (row-indexed) to q=l15 lanes, rescale O^T
      const int srcl = (l15 >> 2) * 16;
      float a0 = __shfl(al[0], srcl), a1 = __shfl(al[1], srcl);
      float a2 = __shfl(al[2], srcl), a3 = __shfl(al[3], srcl);
      const int rr = l15 & 3;
      float aq = (rr & 2) ? ((rr & 1) ? a3 : a2) : ((rr & 1) ? a1 : a0);
#pragma unroll
      for (int dt = 0; dt < 8; ++dt) o[dt] *= aq;
    }
    {  // PV: O^T[d][q] += Vt[d][kv] * P^T[kv][q], kv split in 2 k-tiles of 32
      const bf16x8 pf0 = *(const bf16x8*)&Ps[wave][l15 * 68 + qd * 8];
      const bf16x8 pf1 = *(const bf16x8*)&Ps[wave][l15 * 68 + 32 + qd * 8];
#pragma unroll
      for (int dt = 0; dt < 8; ++dt) {
        const bf16x8 vf0 = *(const bf16x8*)&Vts[(dt * 16 + l15) * 68 + qd * 8];
        const bf16x8 vf1 = *(const bf16x8*)&Vts[(dt * 16 + l15) * 68 + 32 + qd * 8];
        o[dt] = __builtin_amdgcn_mfma_f32_16x16x32_bf16(vf0, pf0, o[dt], 0, 0, 0);
        o[dt] = __builtin_amdgcn_mfma_f32_16x16x32_bf16(vf1, pf1, o[dt], 0, 0, 0);
      }
    }
    __syncthreads();
  }

  {  // normalize by l (q-indexed), packed ushort4 stores of O^T
    const int srcl = (l15 >> 2) * 16;
    float l0 = __shfl(lrow[0], srcl), l1 = __shfl(lrow[1], srcl);
    float l2 = __shfl(lrow[2], srcl), l3 = __shfl(lrow[3], srcl);
    const int rr = l15 & 3;
    float lq = (rr & 2) ? ((rr & 1) ? l3 : l2) : ((rr & 1) ? l1 : l0);
    const float inv = 1.0f / lq;
    const size_t obase = (size_t)(b * SEQ + q0 + wave * 16 + l15) * (NHEAD * HDIM) + h * HDIM;
#pragma unroll
    for (int dt = 0; dt < 8; ++dt) {
      ushort4 pk;
      pk.x = f2bf(o[dt][0] * inv); pk.y = f2bf(o[dt][1] * inv);
      pk.z = f2bf(o[dt][2] * inv); pk.w = f2bf(o[dt][3] * inv);
      *(ushort4*)&ao[obase + dt * 16 + qd * 4] = pk;
    }
  }
}

// ---------------------------------------------------------------------------
extern "C" void kernel_launch(void* const* d_in, const int* in_sizes, int n_in,
                              void* d_out, int out_size, void* d_ws, size_t ws_size,
                              hipStream_t stream) {
  const float* X    = (const float*)d_in[0];
  const float* Wq   = (const float*)d_in[1];
  const float* Wk   = (const float*)d_in[2];
  const float* Wv   = (const float*)d_in[3];
  const float* Wo   = (const float*)d_in[4];
  const float* invf = (const float*)d_in[5];
  const int*   pos  = (const int*)d_in[8];
  float* out = (float*)d_out;

  char* ws = (char*)d_ws;
  u16* Xbf   = (u16*)(ws + 0);
  u16* Wqkvt = (u16*)(ws + 33554432);
  u16* Wot   = (u16*)(ws + 83886080);
  u16* QKV   = (u16*)(ws + 117440512);
  u16* Vt    = (u16*)(ws + 167772160);
  u16* AO    = Xbf;  // reuse: Xbf dead after GEMM1

  dim3 tb32(32, 32);
  cast_f32_bf16<<<16384, 256, 0, stream>>>(X, Xbf, 16777216);
  transpose_f32_bf16<<<dim3(128, 128), tb32, 0, stream>>>(Wq, Wqkvt, 4096, 4096);
  transpose_f32_bf16<<<dim3(32, 128),  tb32, 0, stream>>>(Wk, Wqkvt + (size_t)4096 * 4096, 4096, 1024);
  transpose_f32_bf16<<<dim3(32, 128),  tb32, 0, stream>>>(Wv, Wqkvt + (size_t)5120 * 4096, 4096, 1024);
  transpose_f32_bf16<<<dim3(128, 128), tb32, 0, stream>>>(Wo, Wot, 4096, 4096);

  // grid = flattened (N/256)*(M/256); nbx passed for in-kernel decode
  gemm_bt<0><<<dim3(24 * 16), 512, 0, stream>>>(Xbf, Wqkvt, QKV, Vt, 4096, 6144, 4096, 6144, 24);
  rope_kernel<<<40960, 256, 0, stream>>>(QKV, invf, pos);
  attn_kernel<<<dim3(8, 32, 4), 512, 0, stream>>>(QKV, Vt, AO);
  gemm_bt<1><<<dim3(16 * 16), 512, 0, stream>>>(AO, Wot, out, Vt, 4096, 4096, 4096, 4096, 16);
}